// Round 1
// baseline (47.032 us; speedup 1.0000x reference)
//
#include <hip/hip_runtime.h>
#include <math.h>

#define HWp 65536   // 256*256

__global__ __launch_bounds__(256)
void gp_encoder_kernel(const float* __restrict__ x,
                       const float* __restrict__ Wt,
                       const float* __restrict__ be,
                       float* __restrict__ out)
{
    const int gid = blockIdx.x * 256 + threadIdx.x;   // b*65536 + h*256 + w
    const int b   = gid >> 16;
    const int pix = gid & 0xFFFF;
    const int h   = pix >> 8;
    const int w   = pix & 0xFF;

    // ---------------- conv 3x3 SAME (NCHW / OIHW), 3 -> 30 ----------------
    float xv[27];
    const float* xb = x + b * 3 * HWp;
    #pragma unroll
    for (int ci = 0; ci < 3; ++ci) {
        #pragma unroll
        for (int kh = 0; kh < 3; ++kh) {
            const int hh = h + kh - 1;
            #pragma unroll
            for (int kw = 0; kw < 3; ++kw) {
                const int ww = w + kw - 1;
                float v = 0.f;
                if ((unsigned)hh < 256u && (unsigned)ww < 256u)
                    v = xb[ci * HWp + hh * 256 + ww];
                xv[ci*9 + kh*3 + kw] = v;
            }
        }
    }

    float p[30];
    #pragma unroll
    for (int o = 0; o < 30; ++o) {
        float acc = be[o];                 // uniform -> scalar load
        #pragma unroll
        for (int t = 0; t < 27; ++t)
            acc = fmaf(xv[t], Wt[o*27 + t], acc);  // weights uniform -> s_load
        p[o] = acc;
    }

    float* out_xf = out;
    float* out_m  = out + 4*3*HWp;
    float* out_S  = out + (4*3 + 4*6)*HWp;
    float* out_y  = out + (4*3 + 4*6 + 4*36)*HWp;

    // xf = p[27:30], m = p[0:6] — write early to free registers
    #pragma unroll
    for (int i = 0; i < 3; ++i)
        out_xf[(b*3 + i)*HWp + pix] = p[27 + i];
    #pragma unroll
    for (int c = 0; c < 6; ++c)
        out_m[(b*6 + c)*HWp + pix] = p[c];

    // variances: relu(s)-relu(-s) == s, so d = clip(s^2, 1e-6)
    float d6[6];
    #pragma unroll
    for (int k = 0; k < 6; ++k) {
        const float s = p[6 + k];
        d6[k] = fmaxf(s * s, 1e-6f);
    }

    // ---------------- R = I * G0 * G1 * ... * G14 (column ops) ----------------
    float R[6][6];
    #pragma unroll
    for (int r = 0; r < 6; ++r)
        #pragma unroll
        for (int c = 0; c < 6; ++c)
            R[r][c] = (r == c) ? 1.f : 0.f;

    const int PI_[15] = {0,0,0,0,0,1,1,1,1,2,2,2,3,3,4};
    const int PJ_[15] = {1,2,3,4,5,2,3,4,5,3,4,5,4,5,5};
    #pragma unroll
    for (int k = 0; k < 15; ++k) {
        const int i = PI_[k], j = PJ_[k];
        const float sg  = 1.f / (1.f + expf(-p[12 + k]));
        const float ang = 6.28318530717958647692f * sg;   // 2*pi*sigmoid
        const float c  = cosf(ang);
        const float sn = sinf(ang);
        #pragma unroll
        for (int r = 0; r < 6; ++r) {
            const float ri = R[r][i], rj = R[r][j];
            R[r][i] = c * ri + sn * rj;
            R[r][j] = c * rj - sn * ri;
        }
    }

    // ---------------- S = R diag(d) R^T : write directly ----------------
    #pragma unroll
    for (int m = 0; m < 6; ++m) {
        #pragma unroll
        for (int n = 0; n < 6; ++n) {
            float acc = 0.f;
            #pragma unroll
            for (int k = 0; k < 6; ++k)
                acc += (R[m][k] * d6[k]) * R[n][k];
            out_S[(b*36 + m*6 + n)*HWp + pix] = acc;
        }
    }

    // ---------------- S^-1 first 3 columns, in f64 (amplifying path) ----------------
    double gk[3][6];
    #pragma unroll
    for (int c = 0; c < 3; ++c)
        #pragma unroll
        for (int k = 0; k < 6; ++k)
            gk[c][k] = (double)R[c][k] / (double)d6[k];

    double S1[6][3];
    #pragma unroll
    for (int m = 0; m < 6; ++m) {
        #pragma unroll
        for (int c = 0; c < 3; ++c) {
            double acc = 0.0;
            #pragma unroll
            for (int k = 0; k < 6; ++k)
                acc = fma((double)R[m][k], gk[c][k], acc);
            S1[m][c] = acc;
        }
    }

    // 3x3 inverse of Sxx = S1[0:3][0:3] via adjugate (f64)
    const double a00 = S1[0][0], a01 = S1[0][1], a02 = S1[0][2];
    const double a10 = S1[1][0], a11 = S1[1][1], a12 = S1[1][2];
    const double a20 = S1[2][0], a21 = S1[2][1], a22 = S1[2][2];

    const double det = a00*(a11*a22 - a12*a21)
                     - a01*(a10*a22 - a12*a20)
                     + a02*(a10*a21 - a11*a20);
    const double idet = 1.0 / det;

    double inv[3][3];
    inv[0][0] =  (a11*a22 - a12*a21) * idet;
    inv[0][1] = -(a01*a22 - a02*a21) * idet;
    inv[0][2] =  (a01*a12 - a02*a11) * idet;
    inv[1][0] = -(a10*a22 - a12*a20) * idet;
    inv[1][1] =  (a00*a22 - a02*a20) * idet;
    inv[1][2] = -(a00*a12 - a02*a10) * idet;
    inv[2][0] =  (a10*a21 - a11*a20) * idet;
    inv[2][1] = -(a00*a21 - a01*a20) * idet;
    inv[2][2] =  (a00*a11 - a01*a10) * idet;

    // Q = Syx * inv(Sxx);  Syx = S1[3:6][0:3]
    double Q[3][3];
    #pragma unroll
    for (int r = 0; r < 3; ++r)
        #pragma unroll
        for (int c = 0; c < 3; ++c) {
            double acc = 0.0;
            #pragma unroll
            for (int k = 0; k < 3; ++k)
                acc = fma(S1[3 + r][k], inv[k][c], acc);
            Q[r][c] = acc;
        }

    // y = my + Q (xf - mx);  mx = p[0:3], my = p[3:6], xf = p[27:30]
    #pragma unroll
    for (int i = 0; i < 3; ++i) {
        double acc = (double)p[3 + i];
        #pragma unroll
        for (int n = 0; n < 3; ++n)
            acc = fma(Q[i][n], (double)p[27 + n] - (double)p[n], acc);
        out_y[(b*3 + i)*HWp + pix] = (float)acc;
    }
}

extern "C" void kernel_launch(void* const* d_in, const int* in_sizes, int n_in,
                              void* d_out, int out_size, void* d_ws, size_t ws_size,
                              hipStream_t stream) {
    const float* x  = (const float*)d_in[0];
    const float* Wt = (const float*)d_in[1];
    const float* be = (const float*)d_in[2];
    float* out = (float*)d_out;

    dim3 grid(1024);   // 4*256*256 / 256
    dim3 block(256);
    hipLaunchKernelGGL(gp_encoder_kernel, grid, block, 0, stream, x, Wt, be, out);
}

// Round 2
// 33.278 us; speedup vs baseline: 1.4133x; 1.4133x over previous
//
#include <hip/hip_runtime.h>
#include <math.h>

#define HWp 65536   // 256*256

__global__ __launch_bounds__(256)
void gp_encoder_kernel(const float* __restrict__ x,
                       const float* __restrict__ Wt,
                       const float* __restrict__ be,
                       float* __restrict__ out)
{
    const int gid = blockIdx.x * 256 + threadIdx.x;   // b*65536 + h*256 + w
    const int b   = gid >> 16;
    const int pix = gid & 0xFFFF;
    const int h   = pix >> 8;
    const int w   = pix & 0xFF;

    // ---------------- conv 3x3 SAME (NCHW / OIHW), 3 -> 30 ----------------
    float xv[27];
    const float* xb = x + b * 3 * HWp;
    #pragma unroll
    for (int ci = 0; ci < 3; ++ci) {
        #pragma unroll
        for (int kh = 0; kh < 3; ++kh) {
            const int hh = h + kh - 1;
            #pragma unroll
            for (int kw = 0; kw < 3; ++kw) {
                const int ww = w + kw - 1;
                float v = 0.f;
                if ((unsigned)hh < 256u && (unsigned)ww < 256u)
                    v = xb[ci * HWp + hh * 256 + ww];
                xv[ci*9 + kh*3 + kw] = v;
            }
        }
    }

    float p[30];
    #pragma unroll
    for (int o = 0; o < 30; ++o) {
        float acc = be[o];                 // uniform -> scalar load
        #pragma unroll
        for (int t = 0; t < 27; ++t)
            acc = fmaf(xv[t], Wt[o*27 + t], acc);  // weights uniform -> s_load
        p[o] = acc;
    }

    float* out_xf = out;
    float* out_m  = out + 4*3*HWp;
    float* out_S  = out + (4*3 + 4*6)*HWp;
    float* out_y  = out + (4*3 + 4*6 + 4*36)*HWp;

    // xf = p[27:30], m = p[0:6]
    #pragma unroll
    for (int i = 0; i < 3; ++i)
        out_xf[(b*3 + i)*HWp + pix] = p[27 + i];
    #pragma unroll
    for (int c = 0; c < 6; ++c)
        out_m[(b*6 + c)*HWp + pix] = p[c];

    // variances: relu(s)-relu(-s) == s, so d = clip(s^2, 1e-6)
    float d6[6];
    #pragma unroll
    for (int k = 0; k < 6; ++k) {
        const float s = p[6 + k];
        d6[k] = fmaxf(s * s, 1e-6f);
    }

    // ---------------- R = I * G0 * G1 * ... * G14 (column ops) ----------------
    float R[6][6];
    #pragma unroll
    for (int r = 0; r < 6; ++r)
        #pragma unroll
        for (int c = 0; c < 6; ++c)
            R[r][c] = (r == c) ? 1.f : 0.f;

    const int PI_[15] = {0,0,0,0,0,1,1,1,1,2,2,2,3,3,4};
    const int PJ_[15] = {1,2,3,4,5,2,3,4,5,3,4,5,4,5,5};
    #pragma unroll
    for (int k = 0; k < 15; ++k) {
        const int i = PI_[k], j = PJ_[k];
        const float e  = expf(-p[12 + k]);
        const float sg = __builtin_amdgcn_rcpf(1.f + e);   // sigmoid, ~1 ulp
        // ang = 2*pi*sg ; sin/cos via sinpi/cospi (cheap reduction, 1-2 ulp)
        const float t2 = 2.f * sg;                          // exact
        const float c  = cospif(t2);
        const float sn = sinpif(t2);
        #pragma unroll
        for (int r = 0; r < 6; ++r) {
            const float ri = R[r][i], rj = R[r][j];
            R[r][i] = c * ri + sn * rj;
            R[r][j] = c * rj - sn * ri;
        }
    }

    // ---------------- S = R diag(d) R^T : symmetric, write directly ----------------
    float Rd[6][6];
    #pragma unroll
    for (int m = 0; m < 6; ++m)
        #pragma unroll
        for (int k = 0; k < 6; ++k)
            Rd[m][k] = R[m][k] * d6[k];

    #pragma unroll
    for (int m = 0; m < 6; ++m) {
        #pragma unroll
        for (int n = m; n < 6; ++n) {
            float acc = 0.f;
            #pragma unroll
            for (int k = 0; k < 6; ++k)
                acc = fmaf(Rd[m][k], R[n][k], acc);
            out_S[(b*36 + m*6 + n)*HWp + pix] = acc;
            if (n != m)
                out_S[(b*36 + n*6 + m)*HWp + pix] = acc;
        }
    }

    // ---------------- Q = -S_yy^{-1} S_yx  (exact identity; f64, structured err) ----
    // rd[m][k] = R[3+m][k] * d[k]   (f64 from f32 R,d)
    double rd[3][6];
    #pragma unroll
    for (int m = 0; m < 3; ++m)
        #pragma unroll
        for (int k = 0; k < 6; ++k)
            rd[m][k] = (double)R[3 + m][k] * (double)d6[k];

    double syy[3][3], syx[3][3];
    #pragma unroll
    for (int m = 0; m < 3; ++m) {
        #pragma unroll
        for (int n = 0; n < 3; ++n) {
            double ayy = 0.0, ayx = 0.0;
            #pragma unroll
            for (int k = 0; k < 6; ++k) {
                ayy = fma(rd[m][k], (double)R[3 + n][k], ayy);
                ayx = fma(rd[m][k], (double)R[n][k],     ayx);
            }
            syy[m][n] = ayy;
            syx[m][n] = ayx;
        }
    }

    // 3x3 inverse of syy via adjugate (f64)
    const double a00 = syy[0][0], a01 = syy[0][1], a02 = syy[0][2];
    const double a10 = syy[1][0], a11 = syy[1][1], a12 = syy[1][2];
    const double a20 = syy[2][0], a21 = syy[2][1], a22 = syy[2][2];

    const double det = a00*(a11*a22 - a12*a21)
                     - a01*(a10*a22 - a12*a20)
                     + a02*(a10*a21 - a11*a20);
    const double idet = 1.0 / det;

    double inv[3][3];
    inv[0][0] =  (a11*a22 - a12*a21) * idet;
    inv[0][1] = -(a01*a22 - a02*a21) * idet;
    inv[0][2] =  (a01*a12 - a02*a11) * idet;
    inv[1][0] = -(a10*a22 - a12*a20) * idet;
    inv[1][1] =  (a00*a22 - a02*a20) * idet;
    inv[1][2] = -(a00*a12 - a02*a10) * idet;
    inv[2][0] =  (a10*a21 - a11*a20) * idet;
    inv[2][1] = -(a00*a21 - a01*a20) * idet;
    inv[2][2] =  (a00*a11 - a01*a10) * idet;

    // Qp = S_yy^{-1} S_yx  (Q = -Qp)
    double Qp[3][3];
    #pragma unroll
    for (int r = 0; r < 3; ++r)
        #pragma unroll
        for (int c = 0; c < 3; ++c) {
            double acc = 0.0;
            #pragma unroll
            for (int k = 0; k < 3; ++k)
                acc = fma(inv[r][k], syx[k][c], acc);
            Qp[r][c] = acc;
        }

    // y = my - Qp (xf - mx);  mx = p[0:3], my = p[3:6], xf = p[27:30]
    #pragma unroll
    for (int i = 0; i < 3; ++i) {
        double acc = (double)p[3 + i];
        #pragma unroll
        for (int n = 0; n < 3; ++n)
            acc = fma(-Qp[i][n], (double)p[27 + n] - (double)p[n], acc);
        out_y[(b*3 + i)*HWp + pix] = (float)acc;
    }
}

extern "C" void kernel_launch(void* const* d_in, const int* in_sizes, int n_in,
                              void* d_out, int out_size, void* d_ws, size_t ws_size,
                              hipStream_t stream) {
    const float* x  = (const float*)d_in[0];
    const float* Wt = (const float*)d_in[1];
    const float* be = (const float*)d_in[2];
    float* out = (float*)d_out;

    dim3 grid(1024);   // 4*256*256 / 256
    dim3 block(256);
    hipLaunchKernelGGL(gp_encoder_kernel, grid, block, 0, stream, x, Wt, be, out);
}

// Round 3
// 27.399 us; speedup vs baseline: 1.7165x; 1.2146x over previous
//
#include <hip/hip_runtime.h>
#include <math.h>

#define HWp 65536   // 256*256

__global__ __launch_bounds__(256)
void gp_encoder_kernel(const float* __restrict__ x,
                       const float* __restrict__ Wt,
                       const float* __restrict__ be,
                       float* __restrict__ out)
{
    const int gid = blockIdx.x * 256 + threadIdx.x;   // b*65536 + h*256 + w
    const int b   = gid >> 16;
    const int pix = gid & 0xFFFF;
    const int h   = pix >> 8;
    const int w   = pix & 0xFF;

    // ---------------- conv 3x3 SAME (NCHW / OIHW), 3 -> 30 ----------------
    float xv[27];
    const float* xb = x + b * 3 * HWp;
    #pragma unroll
    for (int ci = 0; ci < 3; ++ci) {
        #pragma unroll
        for (int kh = 0; kh < 3; ++kh) {
            const int hh = h + kh - 1;
            #pragma unroll
            for (int kw = 0; kw < 3; ++kw) {
                const int ww = w + kw - 1;
                float v = 0.f;
                if ((unsigned)hh < 256u && (unsigned)ww < 256u)
                    v = xb[ci * HWp + hh * 256 + ww];
                xv[ci*9 + kh*3 + kw] = v;
            }
        }
    }

    float p[30];
    #pragma unroll
    for (int o = 0; o < 30; ++o) {
        float acc = be[o];                 // uniform -> scalar load
        #pragma unroll
        for (int t = 0; t < 27; ++t)
            acc = fmaf(xv[t], Wt[o*27 + t], acc);  // weights uniform -> s_load
        p[o] = acc;
    }

    float* out_xf = out;
    float* out_m  = out + 4*3*HWp;
    float* out_S  = out + (4*3 + 4*6)*HWp;
    float* out_y  = out + (4*3 + 4*6 + 4*36)*HWp;

    // xf = p[27:30], m = p[0:6]
    #pragma unroll
    for (int i = 0; i < 3; ++i)
        out_xf[(b*3 + i)*HWp + pix] = p[27 + i];
    #pragma unroll
    for (int c = 0; c < 6; ++c)
        out_m[(b*6 + c)*HWp + pix] = p[c];

    // variances: relu(s)-relu(-s) == s, so d = clip(s^2, 1e-6)
    float d6[6];
    #pragma unroll
    for (int k = 0; k < 6; ++k) {
        const float s = p[6 + k];
        d6[k] = fmaxf(s * s, 1e-6f);
    }

    // ------------- all 15 (cos,sin) pairs up front: independent chains -------------
    // ang = 2*pi*sigmoid(t); v_sin/v_cos take REVOLUTIONS, so arg = sigmoid(t).
    float cs[15], ss[15];
    #pragma unroll
    for (int k = 0; k < 15; ++k) {
        const float e  = __expf(-p[12 + k]);                 // native v_exp
        const float sg = __builtin_amdgcn_rcpf(1.f + e);     // sigmoid, ~1 ulp
        cs[k] = __builtin_amdgcn_cosf(sg);                   // cos(2*pi*sg)
        ss[k] = __builtin_amdgcn_sinf(sg);                   // sin(2*pi*sg)
    }

    // ---------------- R = I * G0 * G1 * ... * G14 (column ops) ----------------
    float R[6][6];
    #pragma unroll
    for (int r = 0; r < 6; ++r)
        #pragma unroll
        for (int c = 0; c < 6; ++c)
            R[r][c] = (r == c) ? 1.f : 0.f;

    const int PI_[15] = {0,0,0,0,0,1,1,1,1,2,2,2,3,3,4};
    const int PJ_[15] = {1,2,3,4,5,2,3,4,5,3,4,5,4,5,5};
    #pragma unroll
    for (int k = 0; k < 15; ++k) {
        const int i = PI_[k], j = PJ_[k];
        const float c = cs[k], sn = ss[k];
        #pragma unroll
        for (int r = 0; r < 6; ++r) {
            const float ri = R[r][i], rj = R[r][j];
            R[r][i] = c * ri + sn * rj;
            R[r][j] = c * rj - sn * ri;
        }
    }

    // ------- S = R diag(d) R^T : symmetric; stash S_yx, S_yy for the Q path -------
    float Rd[6][6];
    #pragma unroll
    for (int m = 0; m < 6; ++m)
        #pragma unroll
        for (int k = 0; k < 6; ++k)
            Rd[m][k] = R[m][k] * d6[k];

    float syxf[3][3], syyf[3][3];
    #pragma unroll
    for (int m = 0; m < 6; ++m) {
        #pragma unroll
        for (int n = m; n < 6; ++n) {
            float acc = 0.f;
            #pragma unroll
            for (int k = 0; k < 6; ++k)
                acc = fmaf(Rd[m][k], R[n][k], acc);
            out_S[(b*36 + m*6 + n)*HWp + pix] = acc;
            if (n != m)
                out_S[(b*36 + n*6 + m)*HWp + pix] = acc;
            if (m < 3) { if (n >= 3) syxf[n-3][m] = acc; }
            else       { syyf[m-3][n-3] = acc; if (n != m) syyf[n-3][m-3] = acc; }
        }
    }

    // ---------------- Q = -S_yy^{-1} S_yx  (exact identity; f64 inverse) ----------
    const double a00 = (double)syyf[0][0], a01 = (double)syyf[0][1], a02 = (double)syyf[0][2];
    const double a10 = (double)syyf[1][0], a11 = (double)syyf[1][1], a12 = (double)syyf[1][2];
    const double a20 = (double)syyf[2][0], a21 = (double)syyf[2][1], a22 = (double)syyf[2][2];

    const double det = a00*(a11*a22 - a12*a21)
                     - a01*(a10*a22 - a12*a20)
                     + a02*(a10*a21 - a11*a20);
    const double idet = 1.0 / det;

    double inv[3][3];
    inv[0][0] =  (a11*a22 - a12*a21) * idet;
    inv[0][1] = -(a01*a22 - a02*a21) * idet;
    inv[0][2] =  (a01*a12 - a02*a11) * idet;
    inv[1][0] = -(a10*a22 - a12*a20) * idet;
    inv[1][1] =  (a00*a22 - a02*a20) * idet;
    inv[1][2] = -(a00*a12 - a02*a10) * idet;
    inv[2][0] =  (a10*a21 - a11*a20) * idet;
    inv[2][1] = -(a00*a21 - a01*a20) * idet;
    inv[2][2] =  (a00*a11 - a01*a10) * idet;

    // Qp = S_yy^{-1} S_yx  (Q = -Qp)
    double Qp[3][3];
    #pragma unroll
    for (int r = 0; r < 3; ++r)
        #pragma unroll
        for (int c = 0; c < 3; ++c) {
            double acc = 0.0;
            #pragma unroll
            for (int k = 0; k < 3; ++k)
                acc = fma(inv[r][k], (double)syxf[k][c], acc);
            Qp[r][c] = acc;
        }

    // y = my - Qp (xf - mx);  mx = p[0:3], my = p[3:6], xf = p[27:30]
    #pragma unroll
    for (int i = 0; i < 3; ++i) {
        double acc = (double)p[3 + i];
        #pragma unroll
        for (int n = 0; n < 3; ++n)
            acc = fma(-Qp[i][n], (double)p[27 + n] - (double)p[n], acc);
        out_y[(b*3 + i)*HWp + pix] = (float)acc;
    }
}

extern "C" void kernel_launch(void* const* d_in, const int* in_sizes, int n_in,
                              void* d_out, int out_size, void* d_ws, size_t ws_size,
                              hipStream_t stream) {
    const float* x  = (const float*)d_in[0];
    const float* Wt = (const float*)d_in[1];
    const float* be = (const float*)d_in[2];
    float* out = (float*)d_out;

    dim3 grid(1024);   // 4*256*256 / 256
    dim3 block(256);
    hipLaunchKernelGGL(gp_encoder_kernel, grid, block, 0, stream, x, Wt, be, out);
}

// Round 4
// 23.892 us; speedup vs baseline: 1.9685x; 1.1468x over previous
//
#include <hip/hip_runtime.h>
#include <math.h>

#define HWp 65536   // 256*256

__global__ __launch_bounds__(128)
void gp_encoder_kernel(const float* __restrict__ x,
                       const float* __restrict__ Wt,
                       const float* __restrict__ be,
                       float* __restrict__ out)
{
    // R exchange buffer: [entry][pixel-lane], stride-1 per entry -> conflict-free
    __shared__ float Rsh[36][64];

    const int lane = threadIdx.x & 63;
    const int wid  = threadIdx.x >> 6;          // 0 = wave A (R builder), 1 = wave B (S / y)
    const int gp   = blockIdx.x * 64 + lane;    // global pixel id: b*65536 + h*256 + w
    const int b    = gp >> 16;
    const int pix  = gp & 0xFFFF;
    const int h    = pix >> 8;
    const int w    = pix & 0xFF;

    // ---------------- 3x3x3 neighborhood (both waves load; L1-hit heavy) ----------
    float xv[27];
    const float* xb = x + b * 3 * HWp;
    #pragma unroll
    for (int ci = 0; ci < 3; ++ci) {
        #pragma unroll
        for (int kh = 0; kh < 3; ++kh) {
            const int hh = h + kh - 1;
            #pragma unroll
            for (int kw = 0; kw < 3; ++kw) {
                const int ww = w + kw - 1;
                float v = 0.f;
                if ((unsigned)hh < 256u && (unsigned)ww < 256u)
                    v = xb[ci * HWp + hh * 256 + ww];
                xv[ci*9 + kh*3 + kw] = v;
            }
        }
    }

    float* out_xf = out;
    float* out_m  = out + 4*3*HWp;
    float* out_S  = out + (4*3 + 4*6)*HWp;
    float* out_y  = out + (4*3 + 4*6 + 4*36)*HWp;

    // persists across the barrier in wave-B registers
    float pb[15];      // pb[0..5] = p[0..5] (m), pb[6..11] = p[6..11] (s), pb[12..14] = p[27..29] (xf)
    float d6[6];

    if (wid == 0) {
        // ---------------- wave A: angle channels 12..26 -> R ----------------
        float pa[15];
        #pragma unroll
        for (int o = 0; o < 15; ++o) {
            const int ch = 12 + o;
            float acc = be[ch];
            #pragma unroll
            for (int t = 0; t < 27; ++t)
                acc = fmaf(xv[t], Wt[ch*27 + t], acc);
            pa[o] = acc;
        }

        // all 15 (cos,sin) pairs: ang = 2*pi*sigmoid(t); v_sin/v_cos take revolutions
        float cs[15], ss[15];
        #pragma unroll
        for (int k = 0; k < 15; ++k) {
            const float e  = __expf(-pa[k]);
            const float sg = __builtin_amdgcn_rcpf(1.f + e);
            cs[k] = __builtin_amdgcn_cosf(sg);
            ss[k] = __builtin_amdgcn_sinf(sg);
        }

        // R = I * G0 * ... * G14 (column ops; constant-folded early rotations)
        float R[6][6];
        #pragma unroll
        for (int r = 0; r < 6; ++r)
            #pragma unroll
            for (int c = 0; c < 6; ++c)
                R[r][c] = (r == c) ? 1.f : 0.f;

        const int PI_[15] = {0,0,0,0,0,1,1,1,1,2,2,2,3,3,4};
        const int PJ_[15] = {1,2,3,4,5,2,3,4,5,3,4,5,4,5,5};
        #pragma unroll
        for (int k = 0; k < 15; ++k) {
            const int i = PI_[k], j = PJ_[k];
            const float c = cs[k], sn = ss[k];
            #pragma unroll
            for (int r = 0; r < 6; ++r) {
                const float ri = R[r][i], rj = R[r][j];
                R[r][i] = c * ri + sn * rj;
                R[r][j] = c * rj - sn * ri;
            }
        }

        // publish R
        #pragma unroll
        for (int r = 0; r < 6; ++r)
            #pragma unroll
            for (int c = 0; c < 6; ++c)
                Rsh[r*6 + c][lane] = R[r][c];
    } else {
        // ---------------- wave B: channels 0..11, 27..29 ----------------
        #pragma unroll
        for (int o = 0; o < 15; ++o) {
            const int ch = (o < 12) ? o : (o + 15);
            float acc = be[ch];
            #pragma unroll
            for (int t = 0; t < 27; ++t)
                acc = fmaf(xv[t], Wt[ch*27 + t], acc);
            pb[o] = acc;
        }

        // write m (ch 0..5) and xf (ch 27..29)
        #pragma unroll
        for (int c = 0; c < 6; ++c)
            out_m[(b*6 + c)*HWp + pix] = pb[c];
        #pragma unroll
        for (int i = 0; i < 3; ++i)
            out_xf[(b*3 + i)*HWp + pix] = pb[12 + i];

        // d = clip(s^2, 1e-6)   (relu(s)-relu(-s) == s)
        #pragma unroll
        for (int k = 0; k < 6; ++k) {
            const float s = pb[6 + k];
            d6[k] = fmaxf(s * s, 1e-6f);
        }
    }

    __syncthreads();

    if (wid == 0) return;   // wave A retires, frees SIMD slots

    // ---------------- wave B: S = R diag(d) R^T, Q, y ----------------
    float R[6][6];
    #pragma unroll
    for (int r = 0; r < 6; ++r)
        #pragma unroll
        for (int c = 0; c < 6; ++c)
            R[r][c] = Rsh[r*6 + c][lane];

    float syxf[3][3], syyf[3][3];
    #pragma unroll
    for (int m = 0; m < 6; ++m) {
        float rdm[6];
        #pragma unroll
        for (int k = 0; k < 6; ++k)
            rdm[k] = R[m][k] * d6[k];
        #pragma unroll
        for (int n = m; n < 6; ++n) {
            float acc = 0.f;
            #pragma unroll
            for (int k = 0; k < 6; ++k)
                acc = fmaf(rdm[k], R[n][k], acc);
            out_S[(b*36 + m*6 + n)*HWp + pix] = acc;
            if (n != m)
                out_S[(b*36 + n*6 + m)*HWp + pix] = acc;
            if (m < 3) { if (n >= 3) syxf[n-3][m] = acc; }
            else       { syyf[m-3][n-3] = acc; if (n != m) syyf[n-3][m-3] = acc; }
        }
    }

    // Q = -S_yy^{-1} S_yx  (exact identity; f64 inverse of well-scaled block)
    const double a00 = (double)syyf[0][0], a01 = (double)syyf[0][1], a02 = (double)syyf[0][2];
    const double a10 = (double)syyf[1][0], a11 = (double)syyf[1][1], a12 = (double)syyf[1][2];
    const double a20 = (double)syyf[2][0], a21 = (double)syyf[2][1], a22 = (double)syyf[2][2];

    const double det = a00*(a11*a22 - a12*a21)
                     - a01*(a10*a22 - a12*a20)
                     + a02*(a10*a21 - a11*a20);
    const double idet = 1.0 / det;

    double inv[3][3];
    inv[0][0] =  (a11*a22 - a12*a21) * idet;
    inv[0][1] = -(a01*a22 - a02*a21) * idet;
    inv[0][2] =  (a01*a12 - a02*a11) * idet;
    inv[1][0] = -(a10*a22 - a12*a20) * idet;
    inv[1][1] =  (a00*a22 - a02*a20) * idet;
    inv[1][2] = -(a00*a12 - a02*a10) * idet;
    inv[2][0] =  (a10*a21 - a11*a20) * idet;
    inv[2][1] = -(a00*a21 - a01*a20) * idet;
    inv[2][2] =  (a00*a11 - a01*a10) * idet;

    double Qp[3][3];
    #pragma unroll
    for (int r = 0; r < 3; ++r)
        #pragma unroll
        for (int c = 0; c < 3; ++c) {
            double acc = 0.0;
            #pragma unroll
            for (int k = 0; k < 3; ++k)
                acc = fma(inv[r][k], (double)syxf[k][c], acc);
            Qp[r][c] = acc;
        }

    // y = my - Qp (xf - mx);  mx = pb[0..2], my = pb[3..5], xf = pb[12..14]
    #pragma unroll
    for (int i = 0; i < 3; ++i) {
        double acc = (double)pb[3 + i];
        #pragma unroll
        for (int n = 0; n < 3; ++n)
            acc = fma(-Qp[i][n], (double)pb[12 + n] - (double)pb[n], acc);
        out_y[(b*3 + i)*HWp + pix] = (float)acc;
    }
}

extern "C" void kernel_launch(void* const* d_in, const int* in_sizes, int n_in,
                              void* d_out, int out_size, void* d_ws, size_t ws_size,
                              hipStream_t stream) {
    const float* x  = (const float*)d_in[0];
    const float* Wt = (const float*)d_in[1];
    const float* be = (const float*)d_in[2];
    float* out = (float*)d_out;

    dim3 grid(4096);   // 262144 pixels / 64 per block
    dim3 block(128);   // 2 waves: A (R builder) + B (S / y)
    hipLaunchKernelGGL(gp_encoder_kernel, grid, block, 0, stream, x, Wt, be, out);
}